// Round 1
// baseline (2675.494 us; speedup 1.0000x reference)
//
#include <hip/hip_runtime.h>

#define EMB 64

// One lane per (edge, dim). Wave (64 lanes) == EMB, so the x-gather and the
// y-atomic are each one contiguous 256B access per edge.
__global__ void spmm_atomic(const int* __restrict__ rows,
                            const int* __restrict__ cols,
                            const float* __restrict__ vals,
                            const float* __restrict__ x,
                            float* __restrict__ y,
                            int nnz) {
    int total = nnz * EMB;                 // 2.56e8 < 2^31, fits int
    int stride = gridDim.x * blockDim.x;
    for (int i = blockIdx.x * blockDim.x + threadIdx.x; i < total; i += stride) {
        int e = i >> 6;
        int lane = i & 63;
        int c = cols[e];
        int r = rows[e];
        float v = vals[e];
        float contrib = v * x[((long)c << 6) + lane];
        unsafeAtomicAdd(&y[((long)r << 6) + lane], contrib);
    }
}

// acc = (acc + y) * mul, vectorized float4
__global__ void acc_combine(float* __restrict__ acc,
                            const float* __restrict__ y,
                            int n4, float mul) {
    int i = blockIdx.x * blockDim.x + threadIdx.x;
    if (i < n4) {
        float4 a = ((const float4*)acc)[i];
        float4 b = ((const float4*)y)[i];
        a.x = (a.x + b.x) * mul;
        a.y = (a.y + b.y) * mul;
        a.z = (a.z + b.z) * mul;
        a.w = (a.w + b.w) * mul;
        ((float4*)acc)[i] = a;
    }
}

extern "C" void kernel_launch(void* const* d_in, const int* in_sizes, int n_in,
                              void* d_out, int out_size, void* d_ws, size_t ws_size,
                              hipStream_t stream) {
    const float* user_emb = (const float*)d_in[0];
    const float* item_emb = (const float*)d_in[1];
    const int*   adj_row  = (const int*)d_in[2];
    const int*   adj_col  = (const int*)d_in[3];
    const float* adj_val  = (const float*)d_in[4];
    float* out = (float*)d_out;

    const int n_user  = in_sizes[0] / EMB;
    const int n_item  = in_sizes[1] / EMB;
    const int n_nodes = n_user + n_item;
    const int nnz     = in_sizes[2];
    const size_t node_bytes = (size_t)n_nodes * EMB * sizeof(float);

    float* X = (float*)d_ws;
    float* Y = (float*)((char*)d_ws + node_bytes);

    // X = concat(user_emb, item_emb)
    hipMemcpyAsync(X, user_emb, (size_t)in_sizes[0] * sizeof(float),
                   hipMemcpyDeviceToDevice, stream);
    hipMemcpyAsync(X + (size_t)in_sizes[0], item_emb,
                   (size_t)in_sizes[1] * sizeof(float),
                   hipMemcpyDeviceToDevice, stream);

    // acc = 0 (d_out is poisoned 0xAA before every call)
    hipMemsetAsync(out, 0, node_bytes, stream);

    const int n4 = n_nodes * EMB / 4;
    dim3 blk(256);
    const int spmm_grid = 131072;            // grid-stride, ~2 iters/thread... ample waves
    const int cmb_grid  = (n4 + 255) / 256;

    float* cur = X;
    float* nxt = Y;
    for (int l = 0; l < 3; ++l) {
        hipMemsetAsync(nxt, 0, node_bytes, stream);
        spmm_atomic<<<spmm_grid, blk, 0, stream>>>(adj_row, adj_col, adj_val,
                                                   cur, nxt, nnz);
        const float mul = (l == 2) ? (1.0f / 3.0f) : 1.0f;
        acc_combine<<<cmb_grid, blk, 0, stream>>>(out, nxt, n4, mul);
        float* t = cur; cur = nxt; nxt = t;
    }
}

// Round 2
// 1279.193 us; speedup vs baseline: 2.0915x; 2.0915x over previous
//
#include <hip/hip_runtime.h>

#define EMB 64
#define SCAN_CHUNK 1024

// ---- CSR build: histogram ----
__global__ void hist_kernel(const int* __restrict__ rows, int* __restrict__ counts, int nnz) {
    int i = blockIdx.x * blockDim.x + threadIdx.x;
    if (i < nnz) atomicAdd(&counts[rows[i]], 1);
}

// ---- CSR build: per-1024-chunk sums ----
__global__ void block_reduce_kernel(const int* __restrict__ counts, int* __restrict__ bsums, int n) {
    __shared__ int lds[256];
    int base = blockIdx.x * SCAN_CHUNK;
    int tid = threadIdx.x;
    int s = 0;
    for (int j = 0; j < 4; ++j) {
        int idx = base + j * 256 + tid;
        if (idx < n) s += counts[idx];
    }
    lds[tid] = s; __syncthreads();
    for (int off = 128; off > 0; off >>= 1) {
        if (tid < off) lds[tid] += lds[tid + off];
        __syncthreads();
    }
    if (tid == 0) bsums[blockIdx.x] = lds[0];
}

// ---- CSR build: exclusive scan of chunk sums (single block, generic nb) ----
__global__ void scan_bsums_kernel(int* bsums, int nb) {
    __shared__ int lds[256];
    int tid = threadIdx.x;
    int run = 0;
    for (int base = 0; base < nb; base += 256) {
        int idx = base + tid;
        int v = (idx < nb) ? bsums[idx] : 0;
        int x = v;
        lds[tid] = x; __syncthreads();
        for (int off = 1; off < 256; off <<= 1) {
            int t = (tid >= off) ? lds[tid - off] : 0;
            __syncthreads();
            x += t; lds[tid] = x; __syncthreads();
        }
        if (idx < nb) bsums[idx] = run + x - v;
        int tot = lds[255];
        __syncthreads();
        run += tot;
    }
}

// ---- CSR build: per-chunk exclusive scan + global base -> offs, cursor ----
__global__ void block_scan_kernel(const int* __restrict__ counts, const int* __restrict__ bbase,
                                  int* __restrict__ offs, int* __restrict__ cursor, int n) {
    __shared__ int lds[256];
    int tid = threadIdx.x;
    int base = blockIdx.x * SCAN_CHUNK;
    int v[4]; int run = 0;
    for (int j = 0; j < 4; ++j) {
        int idx = base + tid * 4 + j;
        v[j] = (idx < n) ? counts[idx] : 0;
        run += v[j];
    }
    int x = run;
    lds[tid] = x; __syncthreads();
    for (int off = 1; off < 256; off <<= 1) {
        int t = (tid >= off) ? lds[tid - off] : 0;
        __syncthreads();
        x += t; lds[tid] = x; __syncthreads();
    }
    int prefix = bbase[blockIdx.x] + x - run;
    for (int j = 0; j < 4; ++j) {
        int idx = base + tid * 4 + j;
        if (idx < n) {
            offs[idx] = prefix;
            cursor[idx] = prefix;
            prefix += v[j];
            if (idx == n - 1) offs[n] = prefix;
        }
    }
}

// ---- CSR build: scatter edges into row-sorted order ----
__global__ void scatter_kernel(const int* __restrict__ rows, const int* __restrict__ cols,
                               const float* __restrict__ vals, int* __restrict__ cursor,
                               int* __restrict__ scol, float* __restrict__ sval, int nnz) {
    int i = blockIdx.x * blockDim.x + threadIdx.x;
    if (i < nnz) {
        int p = atomicAdd(&cursor[rows[i]], 1);
        scol[p] = cols[i];
        sval[p] = vals[i];
    }
}

// ---- SpMM: one wave (64 lanes == EMB) per row; no atomics; fused epilogue ----
// mode 0: out = acc;            y = acc        (layer 0)
// mode 1: out += acc;           y = acc        (layer 1)
// mode 2: out = (out+acc)/3                    (layer 2, no y write)
__global__ __launch_bounds__(256) void spmm_csr(
        const int* __restrict__ offs, const int* __restrict__ scol,
        const float* __restrict__ sval,
        const float* __restrict__ x0, const float* __restrict__ x1, int n_split,
        float* __restrict__ y, float* __restrict__ out, int n_rows, int mode) {
    int wid = (blockIdx.x * blockDim.x + threadIdx.x) >> 6;
    if (wid >= n_rows) return;
    int lane = threadIdx.x & 63;
    int r = __builtin_amdgcn_readfirstlane(wid);   // provably wave-uniform -> scalar loads
    int s = offs[r];
    int e = offs[r + 1];
    float acc = 0.f;
    for (int k = s; k < e; ++k) {
        int c = scol[k];
        float v = sval[k];
        const float* xp = (c < n_split) ? (x0 + ((size_t)c << 6))
                                        : (x1 + ((size_t)(c - n_split) << 6));
        acc += v * xp[lane];
    }
    size_t oi = ((size_t)r << 6) + lane;
    if (mode == 0)      { out[oi] = acc;  y[oi] = acc; }
    else if (mode == 1) { out[oi] += acc; y[oi] = acc; }
    else                { out[oi] = (out[oi] + acc) * (1.0f / 3.0f); }
}

extern "C" void kernel_launch(void* const* d_in, const int* in_sizes, int n_in,
                              void* d_out, int out_size, void* d_ws, size_t ws_size,
                              hipStream_t stream) {
    const float* user_emb = (const float*)d_in[0];
    const float* item_emb = (const float*)d_in[1];
    const int*   adj_row  = (const int*)d_in[2];
    const int*   adj_col  = (const int*)d_in[3];
    const float* adj_val  = (const float*)d_in[4];
    float* out = (float*)d_out;

    const int n_user = in_sizes[0] / EMB;
    const int n_item = in_sizes[1] / EMB;
    const int n      = n_user + n_item;
    const int nnz    = in_sizes[2];
    const size_t node_bytes = (size_t)n * EMB * sizeof(float);

    char* p = (char*)d_ws;
    float* A      = (float*)p; p += node_bytes;
    float* B      = (float*)p; p += node_bytes;
    int*   scol   = (int*)p;   p += (size_t)nnz * sizeof(int);
    float* sval   = (float*)p; p += (size_t)nnz * sizeof(float);
    int*   offs   = (int*)p;   p += (size_t)(n + 1) * sizeof(int);
    int*   cursor = (int*)p;   p += (size_t)n * sizeof(int);
    int*   counts = (int*)p;   p += (size_t)n * sizeof(int);
    int*   bsums  = (int*)p;   p += 1024 * sizeof(int);

    const int nb = (n + SCAN_CHUNK - 1) / SCAN_CHUNK;   // 196 chunks
    const int egrid = (nnz + 255) / 256;

    // ---- build CSR (per call; inputs restored before every timed launch) ----
    hipMemsetAsync(counts, 0, (size_t)n * sizeof(int), stream);
    hist_kernel<<<egrid, 256, 0, stream>>>(adj_row, counts, nnz);
    block_reduce_kernel<<<nb, 256, 0, stream>>>(counts, bsums, n);
    scan_bsums_kernel<<<1, 256, 0, stream>>>(bsums, nb);
    block_scan_kernel<<<nb, 256, 0, stream>>>(counts, bsums, offs, cursor, n);
    scatter_kernel<<<egrid, 256, 0, stream>>>(adj_row, adj_col, adj_val,
                                              cursor, scol, sval, nnz);

    // ---- 3 propagation layers, fused accumulate ----
    const int sgrid = (n * EMB + 255) / 256;   // one wave per row
    // layer 0: read concat(user,item) directly
    spmm_csr<<<sgrid, 256, 0, stream>>>(offs, scol, sval,
                                        user_emb, item_emb, n_user,
                                        A, out, n, 0);
    // layer 1: A -> B
    spmm_csr<<<sgrid, 256, 0, stream>>>(offs, scol, sval,
                                        A, A, n,
                                        B, out, n, 1);
    // layer 2: B -> (out only)
    spmm_csr<<<sgrid, 256, 0, stream>>>(offs, scol, sval,
                                        B, B, n,
                                        A, out, n, 2);
}

// Round 3
// 1041.634 us; speedup vs baseline: 2.5686x; 1.2281x over previous
//
#include <hip/hip_runtime.h>

#define EMB 64
#define SCAN_CHUNK 1024

// ---- CSR build: histogram ----
__global__ void hist_kernel(const int* __restrict__ rows, int* __restrict__ counts, int nnz) {
    int i = blockIdx.x * blockDim.x + threadIdx.x;
    if (i < nnz) atomicAdd(&counts[rows[i]], 1);
}

// ---- CSR build: per-1024-chunk sums ----
__global__ void block_reduce_kernel(const int* __restrict__ counts, int* __restrict__ bsums, int n) {
    __shared__ int lds[256];
    int base = blockIdx.x * SCAN_CHUNK;
    int tid = threadIdx.x;
    int s = 0;
    for (int j = 0; j < 4; ++j) {
        int idx = base + j * 256 + tid;
        if (idx < n) s += counts[idx];
    }
    lds[tid] = s; __syncthreads();
    for (int off = 128; off > 0; off >>= 1) {
        if (tid < off) lds[tid] += lds[tid + off];
        __syncthreads();
    }
    if (tid == 0) bsums[blockIdx.x] = lds[0];
}

// ---- CSR build: exclusive scan of chunk sums (single block) ----
__global__ void scan_bsums_kernel(int* bsums, int nb) {
    __shared__ int lds[256];
    int tid = threadIdx.x;
    int run = 0;
    for (int base = 0; base < nb; base += 256) {
        int idx = base + tid;
        int v = (idx < nb) ? bsums[idx] : 0;
        int x = v;
        lds[tid] = x; __syncthreads();
        for (int off = 1; off < 256; off <<= 1) {
            int t = (tid >= off) ? lds[tid - off] : 0;
            __syncthreads();
            x += t; lds[tid] = x; __syncthreads();
        }
        if (idx < nb) bsums[idx] = run + x - v;
        int tot = lds[255];
        __syncthreads();
        run += tot;
    }
}

// ---- CSR build: per-chunk exclusive scan + global base -> offs, cursor ----
__global__ void block_scan_kernel(const int* __restrict__ counts, const int* __restrict__ bbase,
                                  int* __restrict__ offs, int* __restrict__ cursor, int n) {
    __shared__ int lds[256];
    int tid = threadIdx.x;
    int base = blockIdx.x * SCAN_CHUNK;
    int v[4]; int run = 0;
    for (int j = 0; j < 4; ++j) {
        int idx = base + tid * 4 + j;
        v[j] = (idx < n) ? counts[idx] : 0;
        run += v[j];
    }
    int x = run;
    lds[tid] = x; __syncthreads();
    for (int off = 1; off < 256; off <<= 1) {
        int t = (tid >= off) ? lds[tid - off] : 0;
        __syncthreads();
        x += t; lds[tid] = x; __syncthreads();
    }
    int prefix = bbase[blockIdx.x] + x - run;
    for (int j = 0; j < 4; ++j) {
        int idx = base + tid * 4 + j;
        if (idx < n) {
            offs[idx] = prefix;
            cursor[idx] = prefix;
            prefix += v[j];
            if (idx == n - 1) offs[n] = prefix;
        }
    }
}

// ---- CSR build: scatter edges (packed 8B: col | val) into row-sorted order ----
__global__ void scatter_kernel(const int* __restrict__ rows, const int* __restrict__ cols,
                               const float* __restrict__ vals, int* __restrict__ cursor,
                               int2* __restrict__ packed, int nnz) {
    int i = blockIdx.x * blockDim.x + threadIdx.x;
    if (i < nnz) {
        int p = atomicAdd(&cursor[rows[i]], 1);
        packed[p] = make_int2(cols[i], __float_as_int(vals[i]));
    }
}

// ---- SpMM: one wave (64 lanes == EMB) per row; no atomics; fused epilogue ----
// mode 0: out = acc;  y = acc   (layer 0, x split user/item)
// mode 1: out += acc; y = acc   (layer 1)
// mode 2: out = (out+acc)/3     (layer 2, no y write)
__global__ __launch_bounds__(256) void spmm_csr(
        const int* __restrict__ offs, const int2* __restrict__ packed,
        const float* __restrict__ x0, const float* __restrict__ x1, int n_split,
        float* __restrict__ y, float* __restrict__ out, int n_rows, int mode) {
    int wid = (blockIdx.x * blockDim.x + threadIdx.x) >> 6;
    if (wid >= n_rows) return;
    int lane = threadIdx.x & 63;
    int r = __builtin_amdgcn_readfirstlane(wid);   // wave-uniform -> scalar path
    int s = offs[r];
    int e = offs[r + 1];
    float acc0 = 0.f, acc1 = 0.f;
    int k = s;
    for (; k + 1 < e; k += 2) {
        int2 cv0 = packed[k];
        int2 cv1 = packed[k + 1];
        const float* xp0 = (cv0.x < n_split) ? (x0 + ((size_t)cv0.x << 6))
                                             : (x1 + ((size_t)(cv0.x - n_split) << 6));
        const float* xp1 = (cv1.x < n_split) ? (x0 + ((size_t)cv1.x << 6))
                                             : (x1 + ((size_t)(cv1.x - n_split) << 6));
        acc0 += __int_as_float(cv0.y) * xp0[lane];
        acc1 += __int_as_float(cv1.y) * xp1[lane];
    }
    if (k < e) {
        int2 cv = packed[k];
        const float* xp = (cv.x < n_split) ? (x0 + ((size_t)cv.x << 6))
                                           : (x1 + ((size_t)(cv.x - n_split) << 6));
        acc0 += __int_as_float(cv.y) * xp[lane];
    }
    float acc = acc0 + acc1;
    size_t oi = ((size_t)r << 6) + lane;
    if (mode == 0)      { out[oi] = acc;  y[oi] = acc; }
    else if (mode == 1) { out[oi] += acc; y[oi] = acc; }
    else                { out[oi] = (out[oi] + acc) * (1.0f / 3.0f); }
}

extern "C" void kernel_launch(void* const* d_in, const int* in_sizes, int n_in,
                              void* d_out, int out_size, void* d_ws, size_t ws_size,
                              hipStream_t stream) {
    const float* user_emb = (const float*)d_in[0];
    const float* item_emb = (const float*)d_in[1];
    const int*   adj_row  = (const int*)d_in[2];
    const int*   adj_col  = (const int*)d_in[3];
    const float* adj_val  = (const float*)d_in[4];
    float* out = (float*)d_out;

    const int n_user = in_sizes[0] / EMB;
    const int n_item = in_sizes[1] / EMB;
    const int n      = n_user + n_item;
    const int nnz    = in_sizes[2];
    const size_t node_bytes = (size_t)n * EMB * sizeof(float);

    char* p = (char*)d_ws;
    float* A      = (float*)p; p += node_bytes;
    float* B      = (float*)p; p += node_bytes;
    int2*  packed = (int2*)p;  p += (size_t)nnz * sizeof(int2);
    int*   offs   = (int*)p;   p += (size_t)(n + 1) * sizeof(int);
    int*   cursor = (int*)p;   p += (size_t)n * sizeof(int);
    int*   counts = (int*)p;   p += (size_t)n * sizeof(int);
    int*   bsums  = (int*)p;   p += 1024 * sizeof(int);

    const int nb = (n + SCAN_CHUNK - 1) / SCAN_CHUNK;
    const int egrid = (nnz + 255) / 256;

    // ---- build CSR (per call; inputs restored before every timed launch) ----
    hipMemsetAsync(counts, 0, (size_t)n * sizeof(int), stream);
    hist_kernel<<<egrid, 256, 0, stream>>>(adj_row, counts, nnz);
    block_reduce_kernel<<<nb, 256, 0, stream>>>(counts, bsums, n);
    scan_bsums_kernel<<<1, 256, 0, stream>>>(bsums, nb);
    block_scan_kernel<<<nb, 256, 0, stream>>>(counts, bsums, offs, cursor, n);
    scatter_kernel<<<egrid, 256, 0, stream>>>(adj_row, adj_col, adj_val,
                                              cursor, packed, nnz);

    // ---- 3 propagation layers, fused accumulate ----
    const int sgrid = (n * EMB + 255) / 256;   // one wave per row
    spmm_csr<<<sgrid, 256, 0, stream>>>(offs, packed,
                                        user_emb, item_emb, n_user,
                                        A, out, n, 0);
    spmm_csr<<<sgrid, 256, 0, stream>>>(offs, packed,
                                        A, A, n,
                                        B, out, n, 1);
    spmm_csr<<<sgrid, 256, 0, stream>>>(offs, packed,
                                        B, B, n,
                                        A, out, n, 2);
}